// Round 15
// baseline (431.125 us; speedup 1.0000x reference)
//
#include <hip/hip_runtime.h>
#include <hip/hip_fp16.h>

#define TT 800
#define CC 80
#define BB 16
#define SS 128
#define INFV 1e9f
#define NLCB 107          // local chunks per band (856 steps / 8; max s = 848)
#define LAGCH 8           // chunk lag between bands (64 steps >= 49 + 8 + margin)
#define NGC 131           // 107 + 3*8
#define BANDH 200         // rows per band (4 bands x 200 = 800)
#define HALF_PER_BAND (107*50*32)     // 171200
#define HALF_PER_SLOT (4*107*50*32)   // 684800
#define SCALE 14.426950408889634f     // (1/gamma)*log2(e), gamma=0.1
#define SIG_ELEMS (BB*TT*CC)          // 1,024,000 per array
#define SIG_BYTES (3*SIG_ELEMS*2)     // 6,144,000
#define NROWS (3*BB*TT)               // 38,400 rows
#define NORM_BYTES (NROWS*4)          // 153,600

typedef __attribute__((ext_vector_type(8))) _Float16 f16x8;
typedef __attribute__((ext_vector_type(4))) float f32x4;

// Bool masks may arrive as 1-byte numpy bools or int32 — detected at runtime.
__device__ inline bool mask_get(const void* p, int idx, int isInt) {
  if (isInt) return ((const int*)p)[idx] != 0;
  return ((const unsigned char*)p)[idx] != 0;
}

__device__ __forceinline__ float fexp2(float x) {
#if __has_builtin(__builtin_amdgcn_exp2f)
  return __builtin_amdgcn_exp2f(x);
#else
  return __expf(x * 0.6931471805599453f);
#endif
}
__device__ __forceinline__ float flog2(float x) {
#if __has_builtin(__builtin_amdgcn_logf)
  return __builtin_amdgcn_logf(x);
#else
  return __logf(x) * 1.4426950408889634f;
#endif
}
__device__ __forceinline__ float fmin3(float a, float b, float c) {
  return fminf(fminf(a, b), c);
}

// Wave-wide shift-up-by-1 on the VALU pipe (no LDS): DPP compose.
__device__ __forceinline__ float shift_up1(float x) {
  int xi = __builtin_bit_cast(int, x);
  int b = __builtin_amdgcn_update_dpp(xi, xi, 0x143, 0xf, 0xf, false); // row_bcast31
  b = __builtin_amdgcn_update_dpp(b, xi, 0x142, 0xf, 0xf, false);      // row_bcast15
  b = __builtin_amdgcn_update_dpp(b, xi, 0x111, 0xf, 0xf, false);      // row_shr:1
  return __builtin_bit_cast(float, b);
}

// Single block: detect mask element width, compute d_loss into out[2].
__global__ __launch_bounds__(256) void detect_dloss_kernel(
    const float* __restrict__ d, const int* __restrict__ mel_len,
    const void* __restrict__ src_mask, const void* __restrict__ pred_mask,
    int* __restrict__ flags, float* __restrict__ out)
{
  __shared__ int nzs, nzp;
  __shared__ float lb[BB];
  int tid = threadIdx.x;
  if (tid == 0) { nzs = 0; nzp = 0; }
  __syncthreads();
  const unsigned char* sm = (const unsigned char*)src_mask;
  const unsigned char* pm = (const unsigned char*)pred_mask;
  int f = 0;
  for (int i = tid; i < BB * SS; i += 256) if ((i & 3) && sm[i]) f = 1;
  if (f) atomicOr(&nzs, 1);
  f = 0;
  for (int i = tid; i < BB * TT; i += 256) if ((i & 3) && pm[i]) f = 1;
  if (f) atomicOr(&nzp, 1);
  __syncthreads();
  int isIntS = nzs ? 0 : 1;
  if (tid == 0) { flags[0] = isIntS; flags[1] = nzp ? 0 : 1; }

  int b = tid >> 4, k = tid & 15;
  float sd = 0.f, so = 0.f;
  for (int s = k; s < SS; s += 16) {
    bool m = mask_get(src_mask, b * SS + s, isIntS);
    if (!m) { sd += d[b * SS + s]; so += 1.f; }
  }
  for (int off = 8; off; off >>= 1) {
    sd += __shfl_down(sd, off, 16);
    so += __shfl_down(so, off, 16);
  }
  if (k == 0) lb[b] = fabsf((float)mel_len[b] - sd) / so;
  __syncthreads();
  if (tid == 0) {
    float s = 0.f;
    for (int i = 0; i < BB; i++) s += lb[i];
    out[2] = s / (float)BB;
  }
}

// Sigmoid pre-pass: sig[0]=sigmoid(masked mel), sig[1]=sigmoid(post),
// sig[2]=sigmoid(target), each [16][800][80] fp16. 8 elems/thread, vectorized.
__global__ __launch_bounds__(256) void sig_kernel(
    const float* __restrict__ mel, const float* __restrict__ post,
    const float* __restrict__ target, const void* __restrict__ pred_mask,
    const int* __restrict__ flags, __half* __restrict__ sig)
{
  int arr = blockIdx.y;
  const float* src = arr == 0 ? mel : (arr == 1 ? post : target);
  __half* dst = sig + (size_t)arr * SIG_ELEMS;
  int pack = blockIdx.x * 256 + threadIdx.x;
  if (pack >= SIG_ELEMS / 8) return;
  size_t e0 = (size_t)pack * 8;
  float4 v0 = *(const float4*)(src + e0);
  float4 v1 = *(const float4*)(src + e0 + 4);
  if (arr == 0) {
    int bt = (int)(e0 / CC);
    if (mask_get(pred_mask, bt, flags[1])) {
      v0 = make_float4(0.f, 0.f, 0.f, 0.f);
      v1 = make_float4(0.f, 0.f, 0.f, 0.f);
    }
  }
  float f[8] = {v0.x, v0.y, v0.z, v0.w, v1.x, v1.y, v1.z, v1.w};
  union { __half h[8]; uint4 u; } o;
#pragma unroll
  for (int i = 0; i < 8; i++) o.h[i] = __float2half(1.f / (1.f + __expf(-f[i])));
  *(uint4*)(dst + e0) = o.u;
}

// Row squared-norms of all sig rows: norms[arr*12800 + b*800 + t] fp32.
__global__ __launch_bounds__(256) void rnorm_kernel(
    const __half* __restrict__ sig, float* __restrict__ norms)
{
  int row = blockIdx.x * 256 + threadIdx.x;
  if (row >= NROWS) return;
  const __half* p = sig + (size_t)row * CC;
  float s = 0.f;
#pragma unroll
  for (int c = 0; c < CC; c += 8) {
    uint4 u = *(const uint4*)(p + c);
    const __half2* h2 = (const __half2*)&u;
#pragma unroll
    for (int q = 0; q < 4; q++) {
      float2 fv = __half22float2(h2[q]);
      s = fmaf(fv.x, fv.x, s);
      s = fmaf(fv.y, fv.y, s);
    }
  }
  norms[row] = s;
}

// MFMA cost kernel (r13-verified): D[i][j] = |x_i|^2+|y_j|^2-2 x_i.y_j
// (pre-scaled), stored in the 4-band skew-1 chunked layout.
__global__ __launch_bounds__(64) void costm_kernel(
    const __half* __restrict__ sig, const float* __restrict__ norms,
    __half* __restrict__ Dsk, int probBase)
{
  int slot = blockIdx.y;
  int prob = probBase + slot;
  int which = prob >> 4, b = prob & 15;
  const __half* X = sig + (size_t)which * SIG_ELEMS + (size_t)b * TT * CC;
  const __half* Y = sig + (size_t)2 * SIG_ELEMS + (size_t)b * TT * CC;
  const float* nx = norms + which * (BB * TT) + b * TT;
  const float* ny = norms + 2 * (BB * TT) + b * TT;
  int lane = threadIdx.x;
  int mrow = lane & 15, kh = lane >> 4;
  int i0 = blockIdx.x * 16;

  const __half* xr = X + (size_t)(i0 + mrow) * CC;
  uint4 az0 = *(const uint4*)(xr + kh * 8);
  uint4 az1 = *(const uint4*)(xr + 32 + kh * 8);
  uint4 az2 = make_uint4(0, 0, 0, 0);
  if (kh < 2) az2 = *(const uint4*)(xr + 64 + kh * 8);
  f16x8 a0 = __builtin_bit_cast(f16x8, az0);
  f16x8 a1 = __builtin_bit_cast(f16x8, az1);
  f16x8 a2 = __builtin_bit_cast(f16x8, az2);

  int i4 = i0 + (lane >> 4) * 4;
  float4 nx4 = *(const float4*)(nx + i4);

  int band = i4 / BANDH;
  int l = (i4 % BANDH) >> 2;
  __half* obase = Dsk + (size_t)slot * HALF_PER_SLOT +
                  (size_t)band * HALF_PER_BAND + (size_t)l * 32;

  const __half* yr = Y + (size_t)mrow * CC;
  for (int j0 = 0; j0 < TT; j0 += 16) {
    uint4 bz0 = *(const uint4*)(yr + kh * 8);
    uint4 bz1 = *(const uint4*)(yr + 32 + kh * 8);
    uint4 bz2 = make_uint4(0, 0, 0, 0);
    if (kh < 2) bz2 = *(const uint4*)(yr + 64 + kh * 8);
    f32x4 acc = {0.f, 0.f, 0.f, 0.f};
    acc = __builtin_amdgcn_mfma_f32_16x16x32_f16(a0, __builtin_bit_cast(f16x8, bz0), acc, 0, 0, 0);
    acc = __builtin_amdgcn_mfma_f32_16x16x32_f16(a1, __builtin_bit_cast(f16x8, bz1), acc, 0, 0, 0);
    acc = __builtin_amdgcn_mfma_f32_16x16x32_f16(a2, __builtin_bit_cast(f16x8, bz2), acc, 0, 0, 0);

    int j = j0 + mrow;
    float nyv = ny[j];
    int s = j + l;
    int ch = s >> 3, kk = s & 7;
    union { __half h[4]; uint2 u; } cv;
#pragma unroll
    for (int r = 0; r < 4; r++) {
      float nxv = (r == 0) ? nx4.x : (r == 1) ? nx4.y : (r == 2) ? nx4.z : nx4.w;
      cv.h[r] = __float2half((nxv + nyv - 2.0f * acc[r]) * SCALE);
    }
    *(uint2*)(obase + (size_t)ch * 1600 + kk * 4) = cv.u;
    yr += (size_t)16 * CC;
  }
}

// Wave-pipelined soft-DTW, TWO problems per block (512 threads, 8 waves):
// waves 0-3 = problem A bands 0-3, waves 4-7 = problem B bands 0-3. HW puts
// band-k of A and band-k of B on the same SIMD (2 waves/SIMD) — independent
// recurrence chains overlap, filling the ~270cy/step recurrence stall.
// Per-wave structure identical to r12/r13 best (4 rows/lane, skew-1,
// consume-immediately DPP). Shared barrier schedule (same lc per G).
__global__ __launch_bounds__(512) void dtw_kernel(
    const __half* __restrict__ Dsk, float* __restrict__ out, int probBase,
    int gcount)
{
  __shared__ float bnd[2][3][128];
  const int tid = threadIdx.x;
  const int wv = tid >> 6, lane = tid & 63;
  const int pidx = wv >> 2;          // which problem of the pair
  const int w = wv & 3;              // band within problem
  const int slotL = blockIdx.x * 2 + pidx;
  const bool pvalid = slotL < gcount;
  const int slotc = pvalid ? slotL : blockIdx.x * 2;   // clamp: redo A, no write
  const int prob = probBase + slotc;
  const int which = prob >> 4;
  const int lclamp = lane < 49 ? lane : 49;
  const __half* Db = Dsk + (size_t)slotc * HALF_PER_SLOT + (size_t)w * HALF_PER_BAND;

  float cur0 = INFV, cur1 = INFV, cur2 = INFV, cur3 = INFV;
  float up_pipe = INFV, rcarry = INFV, res = 0.f;
  float rbv[8], wrv[8];
#pragma unroll
  for (int k = 0; k < 8; k++) { rbv[k] = INFV; wrv[k] = INFV; }

  uint4 a0, a1, a2, a3, b0, b1, b2, b3;

#define PRE(P0, P1, P2, P3, LCN) do { if ((LCN) < NLCB) {                     \
    const uint4* p_ = (const uint4*)(Db + ((size_t)(LCN) * 50 + lclamp) * 32);\
    P0 = p_[0]; P1 = p_[1]; P2 = p_[2]; P3 = p_[3]; } } while (0)

#define RINGLOAD do { if (w) {                                                \
    const float4* rp_ = (const float4*)&bnd[pidx][w - 1][s0 & 127];           \
    float4 ra_ = rp_[0], rc_ = rp_[1];                                        \
    rbv[0] = ra_.x; rbv[1] = ra_.y; rbv[2] = ra_.z; rbv[3] = ra_.w;           \
    rbv[4] = rc_.x; rbv[5] = rc_.y; rbv[6] = rc_.z; rbv[7] = rc_.w; } } while (0)

#define DO_STEP(K, LOU, HIU) do {                                             \
    const int s_ = s0 + (K);                                                  \
    float nxt_ = shift_up1(cur3);   /* R[4l-1][j] this step (junk lane0) */   \
    unsigned lou_ = (LOU), hiu_ = (HIU);                                      \
    float2 f01 = __half22float2(*(const __half2*)&lou_);                      \
    float2 f23 = __half22float2(*(const __half2*)&hiu_);                      \
    float up_ = nxt_, dg_ = up_pipe;  /* dg = prev step's shuffle = [j-1] */  \
    if (w == 0) { if (lane == 0) { up_ = INFV; dg_ = (s_ == 0) ? 0.0f : INFV; } } \
    else if (lane == 0) { up_ = rbv[(K)]; dg_ = ((K) == 0) ? rcarry : rbv[(K) == 0 ? 0 : (K) - 1]; } \
    float oc0 = cur0, oc1 = cur1, oc2 = cur2;                                 \
    float A0 = fmin3(up_, cur0, dg_);                                         \
    float m0 = f01.x + A0;                                                    \
    float sv0 = fexp2(A0 - up_) + fexp2(A0 - cur0) + fexp2(A0 - dg_);         \
    float A1 = fmin3(m0, cur1, oc0);                                          \
    float m1 = f01.y + A1;                                                    \
    float sv1 = fmaf(sv0, fexp2(A1 - m0), fexp2(A1 - cur1) + fexp2(A1 - oc0));\
    float A2 = fmin3(m1, cur2, oc1);                                          \
    float m2 = f23.x + A2;                                                    \
    float sv2 = fmaf(sv1, fexp2(A2 - m1), fexp2(A2 - cur2) + fexp2(A2 - oc1));\
    float A3 = fmin3(m2, cur3, oc2);                                          \
    float m3 = f23.y + A3;                                                    \
    float sv3 = fmaf(sv2, fexp2(A3 - m2), fexp2(A3 - cur3) + fexp2(A3 - oc2));\
    float r0 = m0 - flog2(sv0);                                               \
    float r1 = m1 - flog2(sv1);                                               \
    float r2 = m2 - flog2(sv2);                                               \
    float r3 = m3 - flog2(sv3);                                               \
    int j_ = s_ - lane;                                                       \
    bool act_ = (lane < 50) && ((unsigned)j_ < 800u);                         \
    cur0 = act_ ? r0 : INFV; cur1 = act_ ? r1 : INFV;                         \
    cur2 = act_ ? r2 : INFV; cur3 = act_ ? r3 : INFV;                         \
    wrv[(K)] = cur3;                                                          \
    if (s_ == 848) res = cur3;                                                \
    up_pipe = nxt_;                                                           \
  } while (0)

#define STEP8(Q0, Q1, Q2, Q3) do {                                            \
    DO_STEP(0, Q0.x, Q0.y); DO_STEP(1, Q0.z, Q0.w);                           \
    DO_STEP(2, Q1.x, Q1.y); DO_STEP(3, Q1.z, Q1.w);                           \
    DO_STEP(4, Q2.x, Q2.y); DO_STEP(5, Q2.z, Q2.w);                           \
    DO_STEP(6, Q3.x, Q3.y); DO_STEP(7, Q3.z, Q3.w); } while (0)

  // prologue: every wave loads its local chunk 0
  PRE(a0, a1, a2, a3, 0);
  __syncthreads();

  for (int G = 0; G < NGC; ++G) {
    const int lc = G - LAGCH * w;
    if (lc >= 0 && lc < NLCB) {
      const int s0 = lc << 3;
      if ((lc & 1) == 0) {
        PRE(b0, b1, b2, b3, lc + 1);
        RINGLOAD;
        STEP8(a0, a1, a2, a3);
      } else {
        PRE(a0, a1, a2, a3, lc + 1);
        RINGLOAD;
        STEP8(b0, b1, b2, b3);
      }
      if (w < 3 && lane == 49) {
#pragma unroll
        for (int k = 0; k < 8; k++) {
          int j = s0 + k - 49;
          if ((unsigned)j < 800u) bnd[pidx][w][j & 127] = wrv[k];
        }
      }
      rcarry = rbv[7];
    }
    __syncthreads();
  }

  // res is pre-scaled; unscale (1/SCALE) and apply 0.001/16 in one constant.
  if (w == 3 && lane == 49 && pvalid) atomicAdd(&out[which], res * 4.3321699e-6f);

#undef PRE
#undef RINGLOAD
#undef DO_STEP
#undef STEP8
}

extern "C" void kernel_launch(void* const* d_in, const int* in_sizes, int n_in,
                              void* d_out, int out_size, void* d_ws, size_t ws_size,
                              hipStream_t stream) {
  const float* d         = (const float*)d_in[0];
  const int*   mel_len   = (const int*)d_in[1];
  const float* mel       = (const float*)d_in[2];
  const float* post      = (const float*)d_in[3];
  const float* target    = (const float*)d_in[4];
  const void*  src_mask  = d_in[5];
  const void*  pred_mask = d_in[6];
  float* out = (float*)d_out;

  int* flags = (int*)d_ws;
  __half* sig = (__half*)((char*)d_ws + 256);
  float* norms = (float*)((char*)d_ws + 256 + SIG_BYTES);
  __half* Dsk = (__half*)((char*)d_ws + 256 + SIG_BYTES + NORM_BYTES);
  size_t per = (size_t)HALF_PER_SLOT * sizeof(__half);  // 1.37 MB per problem
  size_t hdr = 256 + (size_t)SIG_BYTES + (size_t)NORM_BYTES;
  int slots = 0;
  if (ws_size > hdr) slots = (int)((ws_size - hdr) / per);
  if (slots > 32) slots = 32;

  (void)hipMemsetAsync(d_out, 0, 3 * sizeof(float), stream);
  detect_dloss_kernel<<<1, 256, 0, stream>>>(d, mel_len, src_mask, pred_mask, flags, out);
  if (slots < 1) return;
  sig_kernel<<<dim3(500, 3), 256, 0, stream>>>(mel, post, target, pred_mask, flags, sig);
  rnorm_kernel<<<150, 256, 0, stream>>>(sig, norms);

  for (int base = 0; base < 32; base += slots) {
    int g = (32 - base < slots) ? (32 - base) : slots;
    costm_kernel<<<dim3(50, g), 64, 0, stream>>>(sig, norms, Dsk, base);
    dtw_kernel<<<(g + 1) / 2, 512, 0, stream>>>(Dsk, out, base, g);
  }
}

// Round 16
// 289.218 us; speedup vs baseline: 1.4907x; 1.4907x over previous
//
#include <hip/hip_runtime.h>
#include <hip/hip_fp16.h>

#define TT 800
#define CC 80
#define BB 16
#define SS 128
#define INFV 1e9f
#define NLCB 107          // local chunks per band (856 steps / 8; max s = 848)
#define LAGCH 8           // chunk lag between bands (64 steps >= 49 + 8 + margin)
#define NGC 131           // 107 + 3*8
#define BANDH 200         // rows per band (4 bands x 200 = 800)
#define HALF_PER_BAND (107*50*32)     // 171200
#define HALF_PER_SLOT (4*107*50*32)   // 684800
#define SCALE 14.426950408889634f     // (1/gamma)*log2(e), gamma=0.1
#define SIG_ELEMS (BB*TT*CC)          // 1,024,000 per array
#define SIG_BYTES (3*SIG_ELEMS*2)     // 6,144,000
#define NROWS (3*BB*TT)               // 38,400 rows
#define NORM_BYTES (NROWS*4)          // 153,600

typedef __attribute__((ext_vector_type(8))) _Float16 f16x8;
typedef __attribute__((ext_vector_type(4))) float f32x4;

// Bool masks may arrive as 1-byte numpy bools or int32 — detected at runtime.
__device__ inline bool mask_get(const void* p, int idx, int isInt) {
  if (isInt) return ((const int*)p)[idx] != 0;
  return ((const unsigned char*)p)[idx] != 0;
}

__device__ __forceinline__ float fexp2(float x) {
#if __has_builtin(__builtin_amdgcn_exp2f)
  return __builtin_amdgcn_exp2f(x);
#else
  return __expf(x * 0.6931471805599453f);
#endif
}
__device__ __forceinline__ float flog2(float x) {
#if __has_builtin(__builtin_amdgcn_logf)
  return __builtin_amdgcn_logf(x);
#else
  return __logf(x) * 1.4426950408889634f;
#endif
}
__device__ __forceinline__ float fmin3(float a, float b, float c) {
  return fminf(fminf(a, b), c);
}

// Wave-wide shift-up-by-1 on the VALU pipe (no LDS): DPP compose.
__device__ __forceinline__ float shift_up1(float x) {
  int xi = __builtin_bit_cast(int, x);
  int b = __builtin_amdgcn_update_dpp(xi, xi, 0x143, 0xf, 0xf, false); // row_bcast31
  b = __builtin_amdgcn_update_dpp(b, xi, 0x142, 0xf, 0xf, false);      // row_bcast15
  b = __builtin_amdgcn_update_dpp(b, xi, 0x111, 0xf, 0xf, false);      // row_shr:1
  return __builtin_bit_cast(float, b);
}

// Single block: detect mask element width, compute d_loss into out[2].
__global__ __launch_bounds__(256) void detect_dloss_kernel(
    const float* __restrict__ d, const int* __restrict__ mel_len,
    const void* __restrict__ src_mask, const void* __restrict__ pred_mask,
    int* __restrict__ flags, float* __restrict__ out)
{
  __shared__ int nzs, nzp;
  __shared__ float lb[BB];
  int tid = threadIdx.x;
  if (tid == 0) { nzs = 0; nzp = 0; }
  __syncthreads();
  const unsigned char* sm = (const unsigned char*)src_mask;
  const unsigned char* pm = (const unsigned char*)pred_mask;
  int f = 0;
  for (int i = tid; i < BB * SS; i += 256) if ((i & 3) && sm[i]) f = 1;
  if (f) atomicOr(&nzs, 1);
  f = 0;
  for (int i = tid; i < BB * TT; i += 256) if ((i & 3) && pm[i]) f = 1;
  if (f) atomicOr(&nzp, 1);
  __syncthreads();
  int isIntS = nzs ? 0 : 1;
  if (tid == 0) { flags[0] = isIntS; flags[1] = nzp ? 0 : 1; }

  int b = tid >> 4, k = tid & 15;
  float sd = 0.f, so = 0.f;
  for (int s = k; s < SS; s += 16) {
    bool m = mask_get(src_mask, b * SS + s, isIntS);
    if (!m) { sd += d[b * SS + s]; so += 1.f; }
  }
  for (int off = 8; off; off >>= 1) {
    sd += __shfl_down(sd, off, 16);
    so += __shfl_down(so, off, 16);
  }
  if (k == 0) lb[b] = fabsf((float)mel_len[b] - sd) / so;
  __syncthreads();
  if (tid == 0) {
    float s = 0.f;
    for (int i = 0; i < BB; i++) s += lb[i];
    out[2] = s / (float)BB;
  }
}

// Sigmoid pre-pass: sig[0]=sigmoid(masked mel), sig[1]=sigmoid(post),
// sig[2]=sigmoid(target), each [16][800][80] fp16. 8 elems/thread, vectorized.
__global__ __launch_bounds__(256) void sig_kernel(
    const float* __restrict__ mel, const float* __restrict__ post,
    const float* __restrict__ target, const void* __restrict__ pred_mask,
    const int* __restrict__ flags, __half* __restrict__ sig)
{
  int arr = blockIdx.y;
  const float* src = arr == 0 ? mel : (arr == 1 ? post : target);
  __half* dst = sig + (size_t)arr * SIG_ELEMS;
  int pack = blockIdx.x * 256 + threadIdx.x;
  if (pack >= SIG_ELEMS / 8) return;
  size_t e0 = (size_t)pack * 8;
  float4 v0 = *(const float4*)(src + e0);
  float4 v1 = *(const float4*)(src + e0 + 4);
  if (arr == 0) {
    int bt = (int)(e0 / CC);
    if (mask_get(pred_mask, bt, flags[1])) {
      v0 = make_float4(0.f, 0.f, 0.f, 0.f);
      v1 = make_float4(0.f, 0.f, 0.f, 0.f);
    }
  }
  float f[8] = {v0.x, v0.y, v0.z, v0.w, v1.x, v1.y, v1.z, v1.w};
  union { __half h[8]; uint4 u; } o;
#pragma unroll
  for (int i = 0; i < 8; i++) o.h[i] = __float2half(1.f / (1.f + __expf(-f[i])));
  *(uint4*)(dst + e0) = o.u;
}

// Row squared-norms of all sig rows: norms[arr*12800 + b*800 + t] fp32.
__global__ __launch_bounds__(256) void rnorm_kernel(
    const __half* __restrict__ sig, float* __restrict__ norms)
{
  int row = blockIdx.x * 256 + threadIdx.x;
  if (row >= NROWS) return;
  const __half* p = sig + (size_t)row * CC;
  float s = 0.f;
#pragma unroll
  for (int c = 0; c < CC; c += 8) {
    uint4 u = *(const uint4*)(p + c);
    const __half2* h2 = (const __half2*)&u;
#pragma unroll
    for (int q = 0; q < 4; q++) {
      float2 fv = __half22float2(h2[q]);
      s = fmaf(fv.x, fv.x, s);
      s = fmaf(fv.y, fv.y, s);
    }
  }
  norms[row] = s;
}

// MFMA cost kernel: D[i][j] = |x_i|^2 + |y_j|^2 - 2 x_i.y_j  (pre-scaled),
// stored in the skew-1 chunked layout consumed by dtw. One wave per
// (problem, 16-row i-strip); A-frags in registers (K zero-padded 80->96);
// 50 j-tiles x 3 mfma_f32_16x16x32_f16. C/D layout per verified m89 mapping.
__global__ __launch_bounds__(64) void costm_kernel(
    const __half* __restrict__ sig, const float* __restrict__ norms,
    __half* __restrict__ Dsk, int probBase)
{
  int slot = blockIdx.y;
  int prob = probBase + slot;
  int which = prob >> 4, b = prob & 15;
  const __half* X = sig + (size_t)which * SIG_ELEMS + (size_t)b * TT * CC;
  const __half* Y = sig + (size_t)2 * SIG_ELEMS + (size_t)b * TT * CC;
  const float* nx = norms + which * (BB * TT) + b * TT;
  const float* ny = norms + 2 * (BB * TT) + b * TT;
  int lane = threadIdx.x;
  int mrow = lane & 15, kh = lane >> 4;   // A/B frag: row/col = lane&15, k-group = lane>>4
  int i0 = blockIdx.x * 16;

  // A fragments: X row i0+mrow, k = c*32 + kh*8 .. +7 (zero beyond K=80)
  const __half* xr = X + (size_t)(i0 + mrow) * CC;
  uint4 az0 = *(const uint4*)(xr + kh * 8);
  uint4 az1 = *(const uint4*)(xr + 32 + kh * 8);
  uint4 az2 = make_uint4(0, 0, 0, 0);
  if (kh < 2) az2 = *(const uint4*)(xr + 64 + kh * 8);
  f16x8 a0 = __builtin_bit_cast(f16x8, az0);
  f16x8 a1 = __builtin_bit_cast(f16x8, az1);
  f16x8 a2 = __builtin_bit_cast(f16x8, az2);

  // norms for this lane's 4 output rows (C/D: rows (lane>>4)*4 + r)
  int i4 = i0 + (lane >> 4) * 4;
  float4 nx4 = *(const float4*)(nx + i4);

  int band = i4 / BANDH;
  int l = (i4 % BANDH) >> 2;
  __half* obase = Dsk + (size_t)slot * HALF_PER_SLOT +
                  (size_t)band * HALF_PER_BAND + (size_t)l * 32;

  const __half* yr = Y + (size_t)mrow * CC;
  for (int j0 = 0; j0 < TT; j0 += 16) {
    uint4 bz0 = *(const uint4*)(yr + kh * 8);
    uint4 bz1 = *(const uint4*)(yr + 32 + kh * 8);
    uint4 bz2 = make_uint4(0, 0, 0, 0);
    if (kh < 2) bz2 = *(const uint4*)(yr + 64 + kh * 8);
    f32x4 acc = {0.f, 0.f, 0.f, 0.f};
    acc = __builtin_amdgcn_mfma_f32_16x16x32_f16(a0, __builtin_bit_cast(f16x8, bz0), acc, 0, 0, 0);
    acc = __builtin_amdgcn_mfma_f32_16x16x32_f16(a1, __builtin_bit_cast(f16x8, bz1), acc, 0, 0, 0);
    acc = __builtin_amdgcn_mfma_f32_16x16x32_f16(a2, __builtin_bit_cast(f16x8, bz2), acc, 0, 0, 0);

    int j = j0 + mrow;            // C/D col = lane&15
    float nyv = ny[j];
    int s = j + l;
    int ch = s >> 3, kk = s & 7;
    union { __half h[4]; uint2 u; } cv;
#pragma unroll
    for (int r = 0; r < 4; r++) {
      float nxv = (r == 0) ? nx4.x : (r == 1) ? nx4.y : (r == 2) ? nx4.z : nx4.w;
      cv.h[r] = __float2half((nxv + nyv - 2.0f * acc[r]) * SCALE);
    }
    *(uint2*)(obase + (size_t)ch * 1600 + kk * 4) = cv.u;
    yr += (size_t)16 * CC;
  }
}

// Wave-pipelined soft-DTW: 4 waves = 4 bands of 200 rows (lanes 0..49, 4 rows
// each), skew-1 (lane l at col j = s-l), consume-immediately DPP wiring.
// [frozen at round-12/13 best: 228 us, absmax 0]
__global__ __launch_bounds__(256) void dtw_kernel(
    const __half* __restrict__ Dsk, float* __restrict__ out, int probBase)
{
  __shared__ float bnd[3][128];
  const int tid = threadIdx.x;
  const int w = tid >> 6, lane = tid & 63;
  const int slot = blockIdx.x;
  const int prob = probBase + slot;
  const int which = prob >> 4;
  const int lclamp = lane < 49 ? lane : 49;
  const __half* Db = Dsk + (size_t)slot * HALF_PER_SLOT + (size_t)w * HALF_PER_BAND;

  float cur0 = INFV, cur1 = INFV, cur2 = INFV, cur3 = INFV;
  float up_pipe = INFV, rcarry = INFV, res = 0.f;
  float rbv[8], wrv[8];
#pragma unroll
  for (int k = 0; k < 8; k++) { rbv[k] = INFV; wrv[k] = INFV; }

  uint4 a0, a1, a2, a3, b0, b1, b2, b3;

#define PRE(P0, P1, P2, P3, LCN) do { if ((LCN) < NLCB) {                     \
    const uint4* p_ = (const uint4*)(Db + ((size_t)(LCN) * 50 + lclamp) * 32);\
    P0 = p_[0]; P1 = p_[1]; P2 = p_[2]; P3 = p_[3]; } } while (0)

#define RINGLOAD do { if (w) {                                                \
    const float4* rp_ = (const float4*)&bnd[w - 1][s0 & 127];                 \
    float4 ra_ = rp_[0], rc_ = rp_[1];                                        \
    rbv[0] = ra_.x; rbv[1] = ra_.y; rbv[2] = ra_.z; rbv[3] = ra_.w;           \
    rbv[4] = rc_.x; rbv[5] = rc_.y; rbv[6] = rc_.z; rbv[7] = rc_.w; } } while (0)

#define DO_STEP(K, LOU, HIU) do {                                             \
    const int s_ = s0 + (K);                                                  \
    float nxt_ = shift_up1(cur3);   /* R[4l-1][j] this step (junk lane0) */   \
    unsigned lou_ = (LOU), hiu_ = (HIU);                                      \
    float2 f01 = __half22float2(*(const __half2*)&lou_);                      \
    float2 f23 = __half22float2(*(const __half2*)&hiu_);                      \
    float up_ = nxt_, dg_ = up_pipe;  /* dg = prev step's shuffle = [j-1] */  \
    if (w == 0) { if (lane == 0) { up_ = INFV; dg_ = (s_ == 0) ? 0.0f : INFV; } } \
    else if (lane == 0) { up_ = rbv[(K)]; dg_ = ((K) == 0) ? rcarry : rbv[(K) == 0 ? 0 : (K) - 1]; } \
    float oc0 = cur0, oc1 = cur1, oc2 = cur2;                                 \
    float A0 = fmin3(up_, cur0, dg_);                                         \
    float m0 = f01.x + A0;                                                    \
    float sv0 = fexp2(A0 - up_) + fexp2(A0 - cur0) + fexp2(A0 - dg_);         \
    float A1 = fmin3(m0, cur1, oc0);                                          \
    float m1 = f01.y + A1;                                                    \
    float sv1 = fmaf(sv0, fexp2(A1 - m0), fexp2(A1 - cur1) + fexp2(A1 - oc0));\
    float A2 = fmin3(m1, cur2, oc1);                                          \
    float m2 = f23.x + A2;                                                    \
    float sv2 = fmaf(sv1, fexp2(A2 - m1), fexp2(A2 - cur2) + fexp2(A2 - oc1));\
    float A3 = fmin3(m2, cur3, oc2);                                          \
    float m3 = f23.y + A3;                                                    \
    float sv3 = fmaf(sv2, fexp2(A3 - m2), fexp2(A3 - cur3) + fexp2(A3 - oc2));\
    float r0 = m0 - flog2(sv0);                                               \
    float r1 = m1 - flog2(sv1);                                               \
    float r2 = m2 - flog2(sv2);                                               \
    float r3 = m3 - flog2(sv3);                                               \
    int j_ = s_ - lane;                                                       \
    bool act_ = (lane < 50) && ((unsigned)j_ < 800u);                         \
    cur0 = act_ ? r0 : INFV; cur1 = act_ ? r1 : INFV;                         \
    cur2 = act_ ? r2 : INFV; cur3 = act_ ? r3 : INFV;                         \
    wrv[(K)] = cur3;                                                          \
    if (s_ == 848) res = cur3;                                                \
    up_pipe = nxt_;                                                           \
  } while (0)

#define STEP8(Q0, Q1, Q2, Q3) do {                                            \
    DO_STEP(0, Q0.x, Q0.y); DO_STEP(1, Q0.z, Q0.w);                           \
    DO_STEP(2, Q1.x, Q1.y); DO_STEP(3, Q1.z, Q1.w);                           \
    DO_STEP(4, Q2.x, Q2.y); DO_STEP(5, Q2.z, Q2.w);                           \
    DO_STEP(6, Q3.x, Q3.y); DO_STEP(7, Q3.z, Q3.w); } while (0)

  // prologue: every wave loads its local chunk 0
  PRE(a0, a1, a2, a3, 0);
  __syncthreads();

  for (int G = 0; G < NGC; ++G) {
    const int lc = G - LAGCH * w;
    if (lc >= 0 && lc < NLCB) {
      const int s0 = lc << 3;
      if ((lc & 1) == 0) {
        PRE(b0, b1, b2, b3, lc + 1);
        RINGLOAD;
        STEP8(a0, a1, a2, a3);
      } else {
        PRE(a0, a1, a2, a3, lc + 1);
        RINGLOAD;
        STEP8(b0, b1, b2, b3);
      }
      if (w < 3 && lane == 49) {
#pragma unroll
        for (int k = 0; k < 8; k++) {
          int j = s0 + k - 49;
          if ((unsigned)j < 800u) bnd[w][j & 127] = wrv[k];
        }
      }
      rcarry = rbv[7];
    }
    __syncthreads();
  }

  // res is pre-scaled; unscale (1/SCALE) and apply 0.001/16 in one constant.
  if (w == 3 && lane == 49) atomicAdd(&out[which], res * 4.3321699e-6f);

#undef PRE
#undef RINGLOAD
#undef DO_STEP
#undef STEP8
}

extern "C" void kernel_launch(void* const* d_in, const int* in_sizes, int n_in,
                              void* d_out, int out_size, void* d_ws, size_t ws_size,
                              hipStream_t stream) {
  const float* d         = (const float*)d_in[0];
  const int*   mel_len   = (const int*)d_in[1];
  const float* mel       = (const float*)d_in[2];
  const float* post      = (const float*)d_in[3];
  const float* target    = (const float*)d_in[4];
  const void*  src_mask  = d_in[5];
  const void*  pred_mask = d_in[6];
  float* out = (float*)d_out;

  int* flags = (int*)d_ws;
  __half* sig = (__half*)((char*)d_ws + 256);
  float* norms = (float*)((char*)d_ws + 256 + SIG_BYTES);
  __half* Dsk = (__half*)((char*)d_ws + 256 + SIG_BYTES + NORM_BYTES);
  size_t per = (size_t)HALF_PER_SLOT * sizeof(__half);  // 1.37 MB per problem
  size_t hdr = 256 + (size_t)SIG_BYTES + (size_t)NORM_BYTES;
  int slots = 0;
  if (ws_size > hdr) slots = (int)((ws_size - hdr) / per);
  if (slots > 32) slots = 32;

  (void)hipMemsetAsync(d_out, 0, 3 * sizeof(float), stream);
  detect_dloss_kernel<<<1, 256, 0, stream>>>(d, mel_len, src_mask, pred_mask, flags, out);
  if (slots < 1) return;
  sig_kernel<<<dim3(500, 3), 256, 0, stream>>>(mel, post, target, pred_mask, flags, sig);
  rnorm_kernel<<<150, 256, 0, stream>>>(sig, norms);

  for (int base = 0; base < 32; base += slots) {
    int g = (32 - base < slots) ? (32 - base) : slots;
    costm_kernel<<<dim3(50, g), 64, 0, stream>>>(sig, norms, Dsk, base);
    dtw_kernel<<<g, 256, 0, stream>>>(Dsk, out, base);
  }
}

// Round 17
// 279.368 us; speedup vs baseline: 1.5432x; 1.0353x over previous
//
#include <hip/hip_runtime.h>
#include <hip/hip_fp16.h>

#define TT 800
#define CC 80
#define BB 16
#define SS 128
#define INFV 1e9f
#define NLCB 107          // local chunks per band (856 steps / 8; max s = 848)
#define LAGCH 8           // chunk lag between bands (64 steps >= 49 + 8 + margin)
#define NGC 131           // 107 + 3*8
#define BANDH 200         // rows per band (4 bands x 200 = 800)
#define HALF_PER_BAND (107*50*32)     // 171200
#define HALF_PER_SLOT (4*107*50*32)   // 684800
#define SCALE 14.426950408889634f     // (1/gamma)*log2(e), gamma=0.1
#define SIG_ELEMS (BB*TT*CC)          // 1,024,000 per array
#define SIG_BYTES (3*SIG_ELEMS*2)     // 6,144,000
#define NROWS (3*BB*TT)               // 38,400 rows
#define NORM_BYTES (NROWS*4)          // 153,600

typedef __attribute__((ext_vector_type(8))) _Float16 f16x8;
typedef __attribute__((ext_vector_type(4))) float f32x4;

// Bool masks may arrive as 1-byte numpy bools or int32 — detected at runtime.
__device__ inline bool mask_get(const void* p, int idx, int isInt) {
  if (isInt) return ((const int*)p)[idx] != 0;
  return ((const unsigned char*)p)[idx] != 0;
}

__device__ __forceinline__ float fexp2(float x) {
#if __has_builtin(__builtin_amdgcn_exp2f)
  return __builtin_amdgcn_exp2f(x);
#else
  return __expf(x * 0.6931471805599453f);
#endif
}
__device__ __forceinline__ float flog2(float x) {
#if __has_builtin(__builtin_amdgcn_logf)
  return __builtin_amdgcn_logf(x);
#else
  return __logf(x) * 1.4426950408889634f;
#endif
}
__device__ __forceinline__ float fmin3(float a, float b, float c) {
  return fminf(fminf(a, b), c);
}

// Wave-wide shift-up-by-1 on the VALU pipe (no LDS): DPP compose.
__device__ __forceinline__ float shift_up1(float x) {
  int xi = __builtin_bit_cast(int, x);
  int b = __builtin_amdgcn_update_dpp(xi, xi, 0x143, 0xf, 0xf, false); // row_bcast31
  b = __builtin_amdgcn_update_dpp(b, xi, 0x142, 0xf, 0xf, false);      // row_bcast15
  b = __builtin_amdgcn_update_dpp(b, xi, 0x111, 0xf, 0xf, false);      // row_shr:1
  return __builtin_bit_cast(float, b);
}

// Single block: detect mask element width, compute d_loss into out[2],
// and zero out[0..1] (replaces the separate memset dispatch; this kernel
// is first in stream order, before any dtw atomics).
__global__ __launch_bounds__(256) void detect_dloss_kernel(
    const float* __restrict__ d, const int* __restrict__ mel_len,
    const void* __restrict__ src_mask, const void* __restrict__ pred_mask,
    int* __restrict__ flags, float* __restrict__ out)
{
  __shared__ int nzs, nzp;
  __shared__ float lb[BB];
  int tid = threadIdx.x;
  if (tid == 0) { nzs = 0; nzp = 0; out[0] = 0.0f; out[1] = 0.0f; }
  __syncthreads();
  const unsigned char* sm = (const unsigned char*)src_mask;
  const unsigned char* pm = (const unsigned char*)pred_mask;
  int f = 0;
  for (int i = tid; i < BB * SS; i += 256) if ((i & 3) && sm[i]) f = 1;
  if (f) atomicOr(&nzs, 1);
  f = 0;
  for (int i = tid; i < BB * TT; i += 256) if ((i & 3) && pm[i]) f = 1;
  if (f) atomicOr(&nzp, 1);
  __syncthreads();
  int isIntS = nzs ? 0 : 1;
  if (tid == 0) { flags[0] = isIntS; flags[1] = nzp ? 0 : 1; }

  int b = tid >> 4, k = tid & 15;
  float sd = 0.f, so = 0.f;
  for (int s = k; s < SS; s += 16) {
    bool m = mask_get(src_mask, b * SS + s, isIntS);
    if (!m) { sd += d[b * SS + s]; so += 1.f; }
  }
  for (int off = 8; off; off >>= 1) {
    sd += __shfl_down(sd, off, 16);
    so += __shfl_down(so, off, 16);
  }
  if (k == 0) lb[b] = fabsf((float)mel_len[b] - sd) / so;
  __syncthreads();
  if (tid == 0) {
    float s = 0.f;
    for (int i = 0; i < BB; i++) s += lb[i];
    out[2] = s / (float)BB;
  }
}

// Fused sigmoid + row-norm kernel. 320 threads = 32 rows x 10 packs of 8.
// 12800 % 32 == 0 so each block lies entirely within one of {mel,post,target}.
// sig[row*80+..] = fp16 sigmoid (mel masked); norms[row] = sum of the
// fp16-ROUNDED sigmoid squared (bit-matches the previous rnorm pass).
__global__ __launch_bounds__(320) void signorm_kernel(
    const float* __restrict__ mel, const float* __restrict__ post,
    const float* __restrict__ target, const void* __restrict__ pred_mask,
    const int* __restrict__ flags, __half* __restrict__ sig,
    float* __restrict__ norms)
{
  __shared__ float part[320];
  int t = threadIdx.x;
  int row0 = blockIdx.x * 32;
  int rloc = t / 10, pack = t - rloc * 10;
  int row = row0 + rloc;
  int arr = row0 / (BB * TT);               // uniform per block
  const float* src = arr == 0 ? mel : (arr == 1 ? post : target);
  int brow = row - arr * (BB * TT);         // b*800 + t within the array

  size_t e0 = (size_t)brow * CC + pack * 8;
  float4 v0 = *(const float4*)(src + e0);
  float4 v1 = *(const float4*)(src + e0 + 4);
  if (arr == 0 && mask_get(pred_mask, brow, flags[1])) {
    v0 = make_float4(0.f, 0.f, 0.f, 0.f);
    v1 = make_float4(0.f, 0.f, 0.f, 0.f);
  }
  float f[8] = {v0.x, v0.y, v0.z, v0.w, v1.x, v1.y, v1.z, v1.w};
  union { __half h[8]; uint4 u; } o;
  float s = 0.f;
#pragma unroll
  for (int i = 0; i < 8; i++) {
    o.h[i] = __float2half(1.f / (1.f + __expf(-f[i])));
    float hf = __half2float(o.h[i]);
    s = fmaf(hf, hf, s);
  }
  *(uint4*)(sig + (size_t)row * CC + pack * 8) = o.u;
  part[t] = s;
  __syncthreads();
  if (t < 32) {
    float tot = 0.f;
#pragma unroll
    for (int q = 0; q < 10; q++) tot += part[t * 10 + q];
    norms[row0 + t] = tot;
  }
}

// MFMA cost kernel: D[i][j] = |x_i|^2 + |y_j|^2 - 2 x_i.y_j  (pre-scaled),
// stored in the skew-1 chunked layout consumed by dtw. [frozen, r13-verified]
__global__ __launch_bounds__(64) void costm_kernel(
    const __half* __restrict__ sig, const float* __restrict__ norms,
    __half* __restrict__ Dsk, int probBase)
{
  int slot = blockIdx.y;
  int prob = probBase + slot;
  int which = prob >> 4, b = prob & 15;
  const __half* X = sig + (size_t)which * SIG_ELEMS + (size_t)b * TT * CC;
  const __half* Y = sig + (size_t)2 * SIG_ELEMS + (size_t)b * TT * CC;
  const float* nx = norms + which * (BB * TT) + b * TT;
  const float* ny = norms + 2 * (BB * TT) + b * TT;
  int lane = threadIdx.x;
  int mrow = lane & 15, kh = lane >> 4;
  int i0 = blockIdx.x * 16;

  const __half* xr = X + (size_t)(i0 + mrow) * CC;
  uint4 az0 = *(const uint4*)(xr + kh * 8);
  uint4 az1 = *(const uint4*)(xr + 32 + kh * 8);
  uint4 az2 = make_uint4(0, 0, 0, 0);
  if (kh < 2) az2 = *(const uint4*)(xr + 64 + kh * 8);
  f16x8 a0 = __builtin_bit_cast(f16x8, az0);
  f16x8 a1 = __builtin_bit_cast(f16x8, az1);
  f16x8 a2 = __builtin_bit_cast(f16x8, az2);

  int i4 = i0 + (lane >> 4) * 4;
  float4 nx4 = *(const float4*)(nx + i4);

  int band = i4 / BANDH;
  int l = (i4 % BANDH) >> 2;
  __half* obase = Dsk + (size_t)slot * HALF_PER_SLOT +
                  (size_t)band * HALF_PER_BAND + (size_t)l * 32;

  const __half* yr = Y + (size_t)mrow * CC;
  for (int j0 = 0; j0 < TT; j0 += 16) {
    uint4 bz0 = *(const uint4*)(yr + kh * 8);
    uint4 bz1 = *(const uint4*)(yr + 32 + kh * 8);
    uint4 bz2 = make_uint4(0, 0, 0, 0);
    if (kh < 2) bz2 = *(const uint4*)(yr + 64 + kh * 8);
    f32x4 acc = {0.f, 0.f, 0.f, 0.f};
    acc = __builtin_amdgcn_mfma_f32_16x16x32_f16(a0, __builtin_bit_cast(f16x8, bz0), acc, 0, 0, 0);
    acc = __builtin_amdgcn_mfma_f32_16x16x32_f16(a1, __builtin_bit_cast(f16x8, bz1), acc, 0, 0, 0);
    acc = __builtin_amdgcn_mfma_f32_16x16x32_f16(a2, __builtin_bit_cast(f16x8, bz2), acc, 0, 0, 0);

    int j = j0 + mrow;
    float nyv = ny[j];
    int s = j + l;
    int ch = s >> 3, kk = s & 7;
    union { __half h[4]; uint2 u; } cv;
#pragma unroll
    for (int r = 0; r < 4; r++) {
      float nxv = (r == 0) ? nx4.x : (r == 1) ? nx4.y : (r == 2) ? nx4.z : nx4.w;
      cv.h[r] = __float2half((nxv + nyv - 2.0f * acc[r]) * SCALE);
    }
    *(uint2*)(obase + (size_t)ch * 1600 + kk * 4) = cv.u;
    yr += (size_t)16 * CC;
  }
}

// Wave-pipelined soft-DTW: 4 waves = 4 bands of 200 rows (lanes 0..49, 4 rows
// each), skew-1 (lane l at col j = s-l), consume-immediately DPP wiring.
// [frozen at round-12/13 best: 228 us, absmax 0]
__global__ __launch_bounds__(256) void dtw_kernel(
    const __half* __restrict__ Dsk, float* __restrict__ out, int probBase)
{
  __shared__ float bnd[3][128];
  const int tid = threadIdx.x;
  const int w = tid >> 6, lane = tid & 63;
  const int slot = blockIdx.x;
  const int prob = probBase + slot;
  const int which = prob >> 4;
  const int lclamp = lane < 49 ? lane : 49;
  const __half* Db = Dsk + (size_t)slot * HALF_PER_SLOT + (size_t)w * HALF_PER_BAND;

  float cur0 = INFV, cur1 = INFV, cur2 = INFV, cur3 = INFV;
  float up_pipe = INFV, rcarry = INFV, res = 0.f;
  float rbv[8], wrv[8];
#pragma unroll
  for (int k = 0; k < 8; k++) { rbv[k] = INFV; wrv[k] = INFV; }

  uint4 a0, a1, a2, a3, b0, b1, b2, b3;

#define PRE(P0, P1, P2, P3, LCN) do { if ((LCN) < NLCB) {                     \
    const uint4* p_ = (const uint4*)(Db + ((size_t)(LCN) * 50 + lclamp) * 32);\
    P0 = p_[0]; P1 = p_[1]; P2 = p_[2]; P3 = p_[3]; } } while (0)

#define RINGLOAD do { if (w) {                                                \
    const float4* rp_ = (const float4*)&bnd[w - 1][s0 & 127];                 \
    float4 ra_ = rp_[0], rc_ = rp_[1];                                        \
    rbv[0] = ra_.x; rbv[1] = ra_.y; rbv[2] = ra_.z; rbv[3] = ra_.w;           \
    rbv[4] = rc_.x; rbv[5] = rc_.y; rbv[6] = rc_.z; rbv[7] = rc_.w; } } while (0)

#define DO_STEP(K, LOU, HIU) do {                                             \
    const int s_ = s0 + (K);                                                  \
    float nxt_ = shift_up1(cur3);   /* R[4l-1][j] this step (junk lane0) */   \
    unsigned lou_ = (LOU), hiu_ = (HIU);                                      \
    float2 f01 = __half22float2(*(const __half2*)&lou_);                      \
    float2 f23 = __half22float2(*(const __half2*)&hiu_);                      \
    float up_ = nxt_, dg_ = up_pipe;  /* dg = prev step's shuffle = [j-1] */  \
    if (w == 0) { if (lane == 0) { up_ = INFV; dg_ = (s_ == 0) ? 0.0f : INFV; } } \
    else if (lane == 0) { up_ = rbv[(K)]; dg_ = ((K) == 0) ? rcarry : rbv[(K) == 0 ? 0 : (K) - 1]; } \
    float oc0 = cur0, oc1 = cur1, oc2 = cur2;                                 \
    float A0 = fmin3(up_, cur0, dg_);                                         \
    float m0 = f01.x + A0;                                                    \
    float sv0 = fexp2(A0 - up_) + fexp2(A0 - cur0) + fexp2(A0 - dg_);         \
    float A1 = fmin3(m0, cur1, oc0);                                          \
    float m1 = f01.y + A1;                                                    \
    float sv1 = fmaf(sv0, fexp2(A1 - m0), fexp2(A1 - cur1) + fexp2(A1 - oc0));\
    float A2 = fmin3(m1, cur2, oc1);                                          \
    float m2 = f23.x + A2;                                                    \
    float sv2 = fmaf(sv1, fexp2(A2 - m1), fexp2(A2 - cur2) + fexp2(A2 - oc1));\
    float A3 = fmin3(m2, cur3, oc2);                                          \
    float m3 = f23.y + A3;                                                    \
    float sv3 = fmaf(sv2, fexp2(A3 - m2), fexp2(A3 - cur3) + fexp2(A3 - oc2));\
    float r0 = m0 - flog2(sv0);                                               \
    float r1 = m1 - flog2(sv1);                                               \
    float r2 = m2 - flog2(sv2);                                               \
    float r3 = m3 - flog2(sv3);                                               \
    int j_ = s_ - lane;                                                       \
    bool act_ = (lane < 50) && ((unsigned)j_ < 800u);                         \
    cur0 = act_ ? r0 : INFV; cur1 = act_ ? r1 : INFV;                         \
    cur2 = act_ ? r2 : INFV; cur3 = act_ ? r3 : INFV;                         \
    wrv[(K)] = cur3;                                                          \
    if (s_ == 848) res = cur3;                                                \
    up_pipe = nxt_;                                                           \
  } while (0)

#define STEP8(Q0, Q1, Q2, Q3) do {                                            \
    DO_STEP(0, Q0.x, Q0.y); DO_STEP(1, Q0.z, Q0.w);                           \
    DO_STEP(2, Q1.x, Q1.y); DO_STEP(3, Q1.z, Q1.w);                           \
    DO_STEP(4, Q2.x, Q2.y); DO_STEP(5, Q2.z, Q2.w);                           \
    DO_STEP(6, Q3.x, Q3.y); DO_STEP(7, Q3.z, Q3.w); } while (0)

  // prologue: every wave loads its local chunk 0
  PRE(a0, a1, a2, a3, 0);
  __syncthreads();

  for (int G = 0; G < NGC; ++G) {
    const int lc = G - LAGCH * w;
    if (lc >= 0 && lc < NLCB) {
      const int s0 = lc << 3;
      if ((lc & 1) == 0) {
        PRE(b0, b1, b2, b3, lc + 1);
        RINGLOAD;
        STEP8(a0, a1, a2, a3);
      } else {
        PRE(a0, a1, a2, a3, lc + 1);
        RINGLOAD;
        STEP8(b0, b1, b2, b3);
      }
      if (w < 3 && lane == 49) {
#pragma unroll
        for (int k = 0; k < 8; k++) {
          int j = s0 + k - 49;
          if ((unsigned)j < 800u) bnd[w][j & 127] = wrv[k];
        }
      }
      rcarry = rbv[7];
    }
    __syncthreads();
  }

  // res is pre-scaled; unscale (1/SCALE) and apply 0.001/16 in one constant.
  if (w == 3 && lane == 49) atomicAdd(&out[which], res * 4.3321699e-6f);

#undef PRE
#undef RINGLOAD
#undef DO_STEP
#undef STEP8
}

extern "C" void kernel_launch(void* const* d_in, const int* in_sizes, int n_in,
                              void* d_out, int out_size, void* d_ws, size_t ws_size,
                              hipStream_t stream) {
  const float* d         = (const float*)d_in[0];
  const int*   mel_len   = (const int*)d_in[1];
  const float* mel       = (const float*)d_in[2];
  const float* post      = (const float*)d_in[3];
  const float* target    = (const float*)d_in[4];
  const void*  src_mask  = d_in[5];
  const void*  pred_mask = d_in[6];
  float* out = (float*)d_out;

  int* flags = (int*)d_ws;
  __half* sig = (__half*)((char*)d_ws + 256);
  float* norms = (float*)((char*)d_ws + 256 + SIG_BYTES);
  __half* Dsk = (__half*)((char*)d_ws + 256 + SIG_BYTES + NORM_BYTES);
  size_t per = (size_t)HALF_PER_SLOT * sizeof(__half);  // 1.37 MB per problem
  size_t hdr = 256 + (size_t)SIG_BYTES + (size_t)NORM_BYTES;
  int slots = 0;
  if (ws_size > hdr) slots = (int)((ws_size - hdr) / per);
  if (slots > 32) slots = 32;

  detect_dloss_kernel<<<1, 256, 0, stream>>>(d, mel_len, src_mask, pred_mask, flags, out);
  if (slots < 1) return;
  signorm_kernel<<<NROWS / 32, 320, 0, stream>>>(mel, post, target, pred_mask,
                                                 flags, sig, norms);

  for (int base = 0; base < 32; base += slots) {
    int g = (32 - base < slots) ? (32 - base) : slots;
    costm_kernel<<<dim3(50, g), 64, 0, stream>>>(sig, norms, Dsk, base);
    dtw_kernel<<<g, 256, 0, stream>>>(Dsk, out, base);
  }
}